// Round 13
// baseline (86.212 us; speedup 1.0000x reference)
//
#include <hip/hip_runtime.h>
#include <hip/hip_bf16.h>
#include <cstdint>

// Problem constants
#define BROWS 8192
#define DIN   512
#define DH    1024
#define KTOT  1536          // DIN + DH
#define NT    (KTOT / 64)   // 24 K-tiles of 64
// Only gate columns [0,2048) are live: g block [0,1024), i block [1024,2048).
// (reference bug: f_out and o_out both use i_in -> f_in/o_in are dead)

typedef __bf16 bf16x8 __attribute__((ext_vector_type(8)));
typedef __bf16 bf16x4 __attribute__((ext_vector_type(4)));
typedef float  f32x4  __attribute__((ext_vector_type(4)));

__device__ __forceinline__ void load16_to_lds(const void* gptr, void* lptr) {
    __builtin_amdgcn_global_load_lds(
        (const __attribute__((address_space(1))) uint32_t*)gptr,
        (__attribute__((address_space(3))) uint32_t*)lptr,
        16, 0, 0);
}

// ---------- Kernel 1: convert x|h -> bf16 A[8192][1536], PRE-SWIZZLED ----------
// (R4-proven: XOR-8 on the 16B slot within each 128B K-chunk -> 0 bank conflicts)
__global__ __launch_bounds__(256) void cvtA_kernel(
    const float* __restrict__ x, const float* __restrict__ h,
    __bf16* __restrict__ A) {
    int t = blockIdx.x * 256 + threadIdx.x;   // 8192*192 units of 16B
    int row = t / 192;
    int j = t - row * 192;
    int kg = j * 8;
    const float* src = (kg < DIN) ? (x + (size_t)row * DIN + kg)
                                  : (h + (size_t)row * DH + (kg - DIN));
    float4 u = *(const float4*)src;
    float4 v = *(const float4*)(src + 4);
    bf16x8 o = { (__bf16)u.x, (__bf16)u.y, (__bf16)u.z, (__bf16)u.w,
                 (__bf16)v.x, (__bf16)v.y, (__bf16)v.z, (__bf16)v.w };
    int swz = (j * 16) ^ ((row & 7) << 4);
    *(bf16x8*)((char*)A + (size_t)row * 3072 + swz) = o;
}

// ---------- Kernel 2: transpose+convert W cols [0,2048) -> bf16 Bt[2048][1536], PRE-SWIZZLED ----------
__global__ __launch_bounds__(256) void cvtB_kernel(
    const float* __restrict__ Wx, const float* __restrict__ Wh,
    __bf16* __restrict__ Bt) {
    __shared__ float tile[32][33];
    int k0 = blockIdx.x * 32;
    int n0 = blockIdx.y * 32;
    int tx = threadIdx.x;   // 0..31
    int ty = threadIdx.y;   // 0..7
#pragma unroll
    for (int i = 0; i < 4; ++i) {
        int k = k0 + ty + 8 * i;
        float v = (k < DIN) ? Wx[(size_t)k * 4096 + n0 + tx]
                            : Wh[(size_t)(k - DIN) * 4096 + n0 + tx];
        tile[ty + 8 * i][tx] = v;
    }
    __syncthreads();
    int n = n0 + tx;
    int kk = ty * 4;
    bf16x4 o = { (__bf16)tile[kk][tx], (__bf16)tile[kk + 1][tx],
                 (__bf16)tile[kk + 2][tx], (__bf16)tile[kk + 3][tx] };
    int swz = ((k0 + kk) * 2) ^ ((n & 7) << 4);
    *(bf16x4*)((char*)Bt + (size_t)n * 3072 + swz) = o;
}

// ---------- Kernel 3: depth-2 triple-buffered GEMM + fused LSTM epilogue ----------
// Tile 256(M) x 64(n') x {g,i}; B-tile = g 64 + i 64 = 128 rows x 128B.
// LDS/tile: A 32K + B 16K = 48K; x3 buffers = 144 KiB (1 block of 8 waves/CU).
// 8 waves = 4M x 2N; wave = 64M x 32n' x {g,i}; acc 64 VGPR.
// Schedule per tile t:  STAGE(t+2) -> VMW(12) [retires tile t: its 6 loads
// were issued TWO tiles (~1200+ cy) ago -> HBM latency covered] -> BARRIER ->
// 16 ds_read -> LGKM0 -> BARRIER [frees buf(t) for t+3] -> 32 MFMA (pure reg,
// overlaps other waves' staging).  Tail: VMW(6) then VMW(0).

#define BARRIER  do { __builtin_amdgcn_sched_barrier(0); __builtin_amdgcn_s_barrier(); __builtin_amdgcn_sched_barrier(0); } while (0)
#define VMW(n)   do { asm volatile("s_waitcnt vmcnt(" #n ")" ::: "memory"); __builtin_amdgcn_sched_barrier(0); } while (0)
#define LGKM0    do { asm volatile("s_waitcnt lgkmcnt(0)" ::: "memory"); __builtin_amdgcn_sched_barrier(0); } while (0)

// Staging (512 thr): r0 = tid>>3 (0..63), cb = (tid&7)*16. Per-lane LDS ptr =
// waveChunkBase + lane*16 (law m104 satisfied: lane -> row wid*8+(lane>>3)).
// A: 4 issues x 64 rows; B: 2 issues x 64 rows (q=0: g cols, q=1: i cols).
#define STAGE(obuf, kt) do {                                                   \
    _Pragma("unroll")                                                          \
    for (int p_ = 0; p_ < 4; ++p_) {                                           \
        int row_ = p_ * 64 + r0;                                               \
        load16_to_lds(Ab + (size_t)(brow + row_) * 3072 + (kt) * 128 + cb,     \
                      sAb + (obuf) + row_ * 128 + cb);                         \
    }                                                                          \
    load16_to_lds(Bb + (size_t)(bnp + r0) * 3072 + (kt) * 128 + cb,            \
                  sAb + (obuf) + 32768 + r0 * 128 + cb);                       \
    load16_to_lds(Bb + (size_t)(1024 + bnp + r0) * 3072 + (kt) * 128 + cb,     \
                  sAb + (obuf) + 32768 + (64 + r0) * 128 + cb);                \
    __builtin_amdgcn_sched_barrier(0);                                         \
} while (0)

#define READS(obuf) do {                                                       \
    _Pragma("unroll")                                                          \
    for (int m_ = 0; m_ < 4; ++m_) {                                           \
        _Pragma("unroll")                                                      \
        for (int ks_ = 0; ks_ < 2; ++ks_) {                                    \
            aF[m_][ks_] = *(const bf16x8*)(sAb + (obuf)                        \
                + (wrow + m_ * 16 + l15) * 128                                 \
                + ((ks_ * 64 + l4x16) ^ swzkey));                              \
        }                                                                      \
    }                                                                          \
    _Pragma("unroll")                                                          \
    for (int n_ = 0; n_ < 2; ++n_) {                                           \
        _Pragma("unroll")                                                      \
        for (int ks_ = 0; ks_ < 2; ++ks_) {                                    \
            bgF[n_][ks_] = *(const bf16x8*)(sAb + (obuf) + 32768               \
                + (wcol + n_ * 16 + l15) * 128                                 \
                + ((ks_ * 64 + l4x16) ^ swzkey));                              \
            biF[n_][ks_] = *(const bf16x8*)(sAb + (obuf) + 32768               \
                + (64 + wcol + n_ * 16 + l15) * 128                            \
                + ((ks_ * 64 + l4x16) ^ swzkey));                              \
        }                                                                      \
    }                                                                          \
} while (0)

#define MMA_ALL() do {                                                         \
    __builtin_amdgcn_s_setprio(1);                                             \
    _Pragma("unroll")                                                          \
    for (int ks_ = 0; ks_ < 2; ++ks_) {                                        \
        _Pragma("unroll")                                                      \
        for (int m_ = 0; m_ < 4; ++m_) {                                       \
            _Pragma("unroll")                                                  \
            for (int n_ = 0; n_ < 2; ++n_) {                                   \
                accg[m_][n_] = __builtin_amdgcn_mfma_f32_16x16x32_bf16(        \
                    aF[m_][ks_], bgF[n_][ks_], accg[m_][n_], 0, 0, 0);         \
                acci[m_][n_] = __builtin_amdgcn_mfma_f32_16x16x32_bf16(        \
                    aF[m_][ks_], biF[n_][ks_], acci[m_][n_], 0, 0, 0);         \
            }                                                                  \
        }                                                                      \
    }                                                                          \
    __builtin_amdgcn_s_setprio(0);                                             \
    __builtin_amdgcn_sched_barrier(0);                                         \
} while (0)

__global__ __launch_bounds__(512) void lstm_gemm_kernel(
    const __bf16* __restrict__ A,    // [8192][1536] pre-swizzled
    const __bf16* __restrict__ Bt,   // [2048][1536] pre-swizzled
    const float* __restrict__ bias,  // [4096]
    const float* __restrict__ c_in,  // [8192][1024]
    float* __restrict__ out_h,       // [8192][1024]
    float* __restrict__ out_c) {     // [8192][1024]
    // Per buffer (49152 B): A rows 0-255 x 128B at [0,32768);
    //                       B rows 0-127 (g 0-63 | i 64-127) at [32768,49152).
    __shared__ char smem[147456];

    const int tid  = threadIdx.x;
    const int lane = tid & 63;
    const int wid  = tid >> 6;
    const int wr   = wid & 3;          // 4 wave-rows (M)
    const int wc   = wid >> 2;         // 2 wave-cols (n')

    // XCD map: XCD x (= bid%8) owns bands [4x, 4x+4) (A slice 3 MB, L2);
    // band fast within XCD, panel slow. Bijective over 512.
    const int bid   = blockIdx.x;                        // 0..511
    const int band  = (bid & 7) * 4 + ((bid >> 3) & 3);  // 0..31
    const int panel = bid >> 5;                          // 0..15
    const int brow  = band * 256;
    const int bnp   = panel * 64;

    const int l15    = lane & 15;
    const int l4x16  = (lane >> 4) * 16;
    const int swzkey = (l15 & 7) << 4;
    const int wrow   = wr * 64;
    const int wcol   = wc * 32;

    const int r0 = tid >> 3;           // 0..63
    const int cb = (tid & 7) * 16;     // 0..112

    const char* Ab = (const char*)A;
    const char* Bb = (const char*)Bt;
    char* sAb = smem;

    f32x4 accg[4][2], acci[4][2];
#pragma unroll
    for (int mi = 0; mi < 4; ++mi)
#pragma unroll
        for (int ni = 0; ni < 2; ++ni) {
            accg[mi][ni] = (f32x4){0.f, 0.f, 0.f, 0.f};
            acci[mi][ni] = (f32x4){0.f, 0.f, 0.f, 0.f};
        }

    bf16x8 aF[4][2], bgF[2][2], biF[2][2];

    // Prologue: fill depth-2 pipeline.
    STAGE(0, 0);              // tile 0 -> buf 0
    STAGE(49152, 1);          // tile 1 -> buf 1

    int o0 = 0, o1 = 49152, o2 = 98304;   // bufs of tiles t, t+1, t+2
    for (int t = 0; t < NT - 2; ++t) {
        STAGE(o2, t + 2);     // 6 loads; queue = [t(6), t+1(6), t+2(6)]
        VMW(12);              // retire tile t's loads (issued 2 tiles ago)
        BARRIER;
        READS(o0);            // 16 ds_read_b128
        LGKM0;
        BARRIER;              // all waves done reading buf o0 -> reusable
        MMA_ALL();            // 32 MFMA, pure-reg, overlaps others' staging
        int tmp = o0; o0 = o1; o1 = o2; o2 = tmp;
    }
    {   // t = NT-2: queue = [NT-2(6), NT-1(6)]
        VMW(6); BARRIER;
        READS(o0);
        LGKM0; BARRIER;
        MMA_ALL();
        int tmp = o0; o0 = o1; o1 = o2; o2 = tmp;
    }
    {   // t = NT-1: queue = [NT-1(6)]
        VMW(0); BARRIER;
        READS(o0);
        LGKM0;
        MMA_ALL();
    }

    // Epilogue: s = sigmoid(i_in); t = tanh(g_in); c_new = s*(t+c); h_new = tanh(c_new)*s
    const int R0 = brow + wrow;
    const int C0 = bnp + wcol;
    const int l4 = lane >> 4;
#pragma unroll
    for (int ni = 0; ni < 2; ++ni) {
        const int col = C0 + ni * 16 + l15;
        const float bg = bias[col];
        const float bi = bias[1024 + col];
#pragma unroll
        for (int mi = 0; mi < 4; ++mi) {
#pragma unroll
            for (int r = 0; r < 4; ++r) {
                const int row = R0 + mi * 16 + l4 * 4 + r;
                const float g_in = accg[mi][ni][r] + bg;
                const float i_in = acci[mi][ni][r] + bi;
                const float s  = 1.0f / (1.0f + __expf(-i_in));
                const float tg = 2.0f / (1.0f + __expf(-2.0f * g_in)) - 1.0f;
                const float cv = c_in[(size_t)row * DH + col];
                const float cn = s * (tg + cv);
                const float hn = (2.0f / (1.0f + __expf(-2.0f * cn)) - 1.0f) * s;
                out_h[(size_t)row * DH + col] = hn;
                out_c[(size_t)row * DH + col] = cn;
            }
        }
    }
}

extern "C" void kernel_launch(void* const* d_in, const int* in_sizes, int n_in,
                              void* d_out, int out_size, void* d_ws, size_t ws_size,
                              hipStream_t stream) {
    const float* x  = (const float*)d_in[0];
    const float* h  = (const float*)d_in[1];
    const float* c  = (const float*)d_in[2];
    const float* Wx = (const float*)d_in[3];
    const float* Wh = (const float*)d_in[4];
    const float* b  = (const float*)d_in[5];

    __bf16* A  = (__bf16*)d_ws;                                     // 25,165,824 B
    __bf16* Bt = (__bf16*)((char*)d_ws + (size_t)BROWS * KTOT * 2); // 6,291,456 B

    float* out_h = (float*)d_out;
    float* out_c = out_h + (size_t)BROWS * DH;

    cvtA_kernel<<<(BROWS * (KTOT / 8)) / 256, 256, 0, stream>>>(x, h, A);
    cvtB_kernel<<<dim3(KTOT / 32, 2048 / 32), dim3(32, 8), 0, stream>>>(Wx, Wh, Bt);
    lstm_gemm_kernel<<<512, 512, 0, stream>>>(A, Bt, b, c, out_h, out_c);
}

// Round 14
// 82.123 us; speedup vs baseline: 1.0498x; 1.0498x over previous
//
#include <hip/hip_runtime.h>
#include <hip/hip_bf16.h>
#include <cstdint>

// Problem constants
#define BROWS 8192
#define DIN   512
#define DH    1024
#define KTOT  1536          // DIN + DH
#define NT    (KTOT / 64)   // 24 K-tiles of 64
// Only gate columns [0,2048) are live: g block [0,1024), i block [1024,2048).
// (reference bug: f_out and o_out both use i_in -> f_in/o_in are dead)

typedef __bf16 bf16x8 __attribute__((ext_vector_type(8)));
typedef __bf16 bf16x4 __attribute__((ext_vector_type(4)));
typedef float  f32x4  __attribute__((ext_vector_type(4)));

__device__ __forceinline__ void load16_to_lds(const void* gptr, void* lptr) {
    __builtin_amdgcn_global_load_lds(
        (const __attribute__((address_space(1))) uint32_t*)gptr,
        (__attribute__((address_space(3))) uint32_t*)lptr,
        16, 0, 0);
}

// ---------- Kernel 1: convert x|h -> bf16 A[8192][1536], PRE-SWIZZLED ----------
// (R4-proven: XOR-8 on the 16B slot within each 128B K-chunk -> 0 bank conflicts)
__global__ __launch_bounds__(256) void cvtA_kernel(
    const float* __restrict__ x, const float* __restrict__ h,
    __bf16* __restrict__ A) {
    int t = blockIdx.x * 256 + threadIdx.x;   // 8192*192 units of 16B
    int row = t / 192;
    int j = t - row * 192;
    int kg = j * 8;
    const float* src = (kg < DIN) ? (x + (size_t)row * DIN + kg)
                                  : (h + (size_t)row * DH + (kg - DIN));
    float4 u = *(const float4*)src;
    float4 v = *(const float4*)(src + 4);
    bf16x8 o = { (__bf16)u.x, (__bf16)u.y, (__bf16)u.z, (__bf16)u.w,
                 (__bf16)v.x, (__bf16)v.y, (__bf16)v.z, (__bf16)v.w };
    int swz = (j * 16) ^ ((row & 7) << 4);
    *(bf16x8*)((char*)A + (size_t)row * 3072 + swz) = o;
}

// ---------- Kernel 2: transpose+convert W cols [0,2048) -> bf16 Bt[2048][1536], PRE-SWIZZLED ----------
__global__ __launch_bounds__(256) void cvtB_kernel(
    const float* __restrict__ Wx, const float* __restrict__ Wh,
    __bf16* __restrict__ Bt) {
    __shared__ float tile[32][33];
    int k0 = blockIdx.x * 32;
    int n0 = blockIdx.y * 32;
    int tx = threadIdx.x;   // 0..31
    int ty = threadIdx.y;   // 0..7
#pragma unroll
    for (int i = 0; i < 4; ++i) {
        int k = k0 + ty + 8 * i;
        float v = (k < DIN) ? Wx[(size_t)k * 4096 + n0 + tx]
                            : Wh[(size_t)(k - DIN) * 4096 + n0 + tx];
        tile[ty + 8 * i][tx] = v;
    }
    __syncthreads();
    int n = n0 + tx;
    int kk = ty * 4;
    bf16x4 o = { (__bf16)tile[kk][tx], (__bf16)tile[kk + 1][tx],
                 (__bf16)tile[kk + 2][tx], (__bf16)tile[kk + 3][tx] };
    int swz = ((k0 + kk) * 2) ^ ((n & 7) << 4);
    *(bf16x4*)((char*)Bt + (size_t)n * 3072 + swz) = o;
}

// ---------- Kernel 3: register-pipelined GEMM + fused LSTM epilogue ----------
// Geometry = R4 (proven): tile 256M x 128n' x {g,i}, BK=64, 8 waves (4M x 2N),
// LDS 2 x (A 32K + B 32K) = 128 KiB. NEW: each K-tile splits into 2 ks-phases
// with DOUBLE-BUFFERED FRAGMENT REGS (sets X,Y; 48 VGPR each):
//   P0: issue 12 ds_read for set Y (tile t, ks1); lgkmcnt(12) -> set X done
//       (DS completes in-order); 32 MFMA on X  [reads || MFMA overlap]
//   P1: lgkmcnt(0) -> my reads of buf(t) done; BARRIER -> buf(t) free (WAR);
//       STAGE(t+2 -> buf(t)); VMW(8) -> t+1 landed (issued a full tile ago);
//       BARRIER; issue 12 ds_read for set X (tile t+1, ks0); 32 MFMA on Y.
// Per tile: 2 barriers, 24 ds_read, 8 stage-loads, 64 MFMA.

#define BARRIER  do { __builtin_amdgcn_sched_barrier(0); __builtin_amdgcn_s_barrier(); __builtin_amdgcn_sched_barrier(0); } while (0)
#define VMW(n)   do { asm volatile("s_waitcnt vmcnt(" #n ")" ::: "memory"); __builtin_amdgcn_sched_barrier(0); } while (0)
#define LGKM(n)  do { asm volatile("s_waitcnt lgkmcnt(" #n ")" ::: "memory"); __builtin_amdgcn_sched_barrier(0); } while (0)

// Staging: r0 = tid>>3 (0..63), cb = (tid&7)*16; per-lane LDS = chunk + lane*16.
#define STAGE(cur, kt) do {                                                    \
    _Pragma("unroll")                                                          \
    for (int p_ = 0; p_ < 4; ++p_) {                                           \
        int row_ = p_ * 64 + r0;                                               \
        load16_to_lds(Ab + (size_t)(brow + row_) * 3072 + (kt) * 128 + cb,     \
                      smem + (cur) * 65536 + row_ * 128 + cb);                 \
    }                                                                          \
    _Pragma("unroll")                                                          \
    for (int p_ = 0; p_ < 2; ++p_) {                                           \
        int row_ = p_ * 64 + r0;                                               \
        load16_to_lds(Bb + (size_t)(bnp + row_) * 3072 + (kt) * 128 + cb,      \
                      smem + (cur) * 65536 + 32768 + row_ * 128 + cb);         \
        load16_to_lds(Bb + (size_t)(1024 + bnp + row_) * 3072                  \
                          + (kt) * 128 + cb,                                   \
                      smem + (cur) * 65536 + 32768 + (128 + row_) * 128 + cb); \
    }                                                                          \
    __builtin_amdgcn_sched_barrier(0);                                         \
} while (0)

// 12 ds_read_b128 for one ks-phase into (aT, bgT, biT)
#define READF(ks, cur, aT, bgT, biT) do {                                      \
    const int kb_ = (((ks) * 64 + l4x16) ^ swzkey);                            \
    _Pragma("unroll")                                                          \
    for (int m_ = 0; m_ < 4; ++m_)                                             \
        aT[m_] = *(const bf16x8*)(smem + (cur) * 65536                         \
            + (wrow + m_ * 16 + l15) * 128 + kb_);                             \
    _Pragma("unroll")                                                          \
    for (int n_ = 0; n_ < 4; ++n_) {                                           \
        bgT[n_] = *(const bf16x8*)(smem + (cur) * 65536 + 32768                \
            + (wcol + n_ * 16 + l15) * 128 + kb_);                             \
        biT[n_] = *(const bf16x8*)(smem + (cur) * 65536 + 32768                \
            + (128 + wcol + n_ * 16 + l15) * 128 + kb_);                       \
    }                                                                          \
    __builtin_amdgcn_sched_barrier(0);                                         \
} while (0)

// 32 MFMA on one phase-set
#define MMA(aT, bgT, biT) do {                                                 \
    __builtin_amdgcn_s_setprio(1);                                             \
    _Pragma("unroll")                                                          \
    for (int m_ = 0; m_ < 4; ++m_) {                                           \
        _Pragma("unroll")                                                      \
        for (int n_ = 0; n_ < 4; ++n_) {                                       \
            accg[m_][n_] = __builtin_amdgcn_mfma_f32_16x16x32_bf16(            \
                aT[m_], bgT[n_], accg[m_][n_], 0, 0, 0);                       \
            acci[m_][n_] = __builtin_amdgcn_mfma_f32_16x16x32_bf16(            \
                aT[m_], biT[n_], acci[m_][n_], 0, 0, 0);                       \
        }                                                                      \
    }                                                                          \
    __builtin_amdgcn_s_setprio(0);                                             \
    __builtin_amdgcn_sched_barrier(0);                                         \
} while (0)

__global__ __launch_bounds__(512) void lstm_gemm_kernel(
    const __bf16* __restrict__ A,    // [8192][1536] pre-swizzled
    const __bf16* __restrict__ Bt,   // [2048][1536] pre-swizzled
    const float* __restrict__ bias,  // [4096]
    const float* __restrict__ c_in,  // [8192][1024]
    float* __restrict__ out_h,       // [8192][1024]
    float* __restrict__ out_c) {     // [8192][1024]
    // Per buffer (65536 B): A rows 0-255 x 128B at [0,32768);
    //                       B rows 0-255 (g 0-127 | i 128-255) at [32768,65536).
    __shared__ char smem[131072];

    const int tid  = threadIdx.x;
    const int lane = tid & 63;
    const int wid  = tid >> 6;
    const int wr   = wid & 3;          // 4 wave-rows (M)
    const int wc   = wid >> 2;         // 2 wave-cols (n')

    // XCD map (R9-proven, FETCH=67MB): XCD x (= bid%8) owns bands [4x,4x+4).
    const int bid   = blockIdx.x;                        // 0..255
    const int band  = (bid & 7) * 4 + ((bid >> 3) & 3);  // 0..31
    const int panel = bid >> 5;                          // 0..7
    const int brow  = band * 256;
    const int bnp   = panel * 128;

    const int l15    = lane & 15;
    const int l4x16  = (lane >> 4) * 16;
    const int swzkey = (l15 & 7) << 4;
    const int wrow   = wr * 64;
    const int wcol   = wc * 64;

    const int r0 = tid >> 3;           // 0..63
    const int cb = (tid & 7) * 16;     // 0..112

    const char* Ab = (const char*)A;
    const char* Bb = (const char*)Bt;

    f32x4 accg[4][4], acci[4][4];
#pragma unroll
    for (int mi = 0; mi < 4; ++mi)
#pragma unroll
        for (int ni = 0; ni < 4; ++ni) {
            accg[mi][ni] = (f32x4){0.f, 0.f, 0.f, 0.f};
            acci[mi][ni] = (f32x4){0.f, 0.f, 0.f, 0.f};
        }

    bf16x8 aX[4], bgX[4], biX[4];      // phase-set X (48 VGPR)
    bf16x8 aY[4], bgY[4], biY[4];      // phase-set Y (48 VGPR)

    // Prologue: stage tiles 0,1; read tile0 ks0 into X.
    STAGE(0, 0);
    STAGE(1, 1);
    VMW(8);                            // tile0's 8 loads landed
    BARRIER;
    READF(0, 0, aX, bgX, biX);

    for (int t = 0; t < NT; ++t) {
        const int cur = t & 1;
        // P0: read Y (tile t, ks1) || MFMA X (tile t, ks0)
        READF(1, cur, aY, bgY, biY);
        LGKM(12);                      // X's 12 reads done (DS in-order)
        MMA(aX, bgX, biX);
        // P1: free buf(t), stage t+2, sync t+1, read X' || MFMA Y
        LGKM(0);                       // Y's reads done -> buf(t) fully read
        BARRIER;                       // ... by ALL waves (WAR safe)
        if (t + 2 < NT) {
            STAGE(cur, t + 2);         // queue: [t+1(8), t+2(8)]
        }
        if (t + 1 < NT) {
            if (t + 2 < NT) { VMW(8); } else { VMW(0); }
            BARRIER;                   // tile t+1 staged, all waves
            READF(0, cur ^ 1, aX, bgX, biX);
        }
        MMA(aY, bgY, biY);
    }

    // Epilogue: s = sigmoid(i_in); t = tanh(g_in); c_new = s*(t+c); h_new = tanh(c_new)*s
    const int R0 = brow + wrow;
    const int C0 = bnp + wcol;
    const int l4 = lane >> 4;
#pragma unroll
    for (int ni = 0; ni < 4; ++ni) {
        const int col = C0 + ni * 16 + l15;
        const float bg = bias[col];
        const float bi = bias[1024 + col];
#pragma unroll
        for (int mi = 0; mi < 4; ++mi) {
#pragma unroll
            for (int r = 0; r < 4; ++r) {
                const int row = R0 + mi * 16 + l4 * 4 + r;
                const float g_in = accg[mi][ni][r] + bg;
                const float i_in = acci[mi][ni][r] + bi;
                const float s  = 1.0f / (1.0f + __expf(-i_in));
                const float tg = 2.0f / (1.0f + __expf(-2.0f * g_in)) - 1.0f;
                const float cv = c_in[(size_t)row * DH + col];
                const float cn = s * (tg + cv);
                const float hn = (2.0f / (1.0f + __expf(-2.0f * cn)) - 1.0f) * s;
                out_h[(size_t)row * DH + col] = hn;
                out_c[(size_t)row * DH + col] = cn;
            }
        }
    }
}

extern "C" void kernel_launch(void* const* d_in, const int* in_sizes, int n_in,
                              void* d_out, int out_size, void* d_ws, size_t ws_size,
                              hipStream_t stream) {
    const float* x  = (const float*)d_in[0];
    const float* h  = (const float*)d_in[1];
    const float* c  = (const float*)d_in[2];
    const float* Wx = (const float*)d_in[3];
    const float* Wh = (const float*)d_in[4];
    const float* b  = (const float*)d_in[5];

    __bf16* A  = (__bf16*)d_ws;                                     // 25,165,824 B
    __bf16* Bt = (__bf16*)((char*)d_ws + (size_t)BROWS * KTOT * 2); // 6,291,456 B

    float* out_h = (float*)d_out;
    float* out_c = out_h + (size_t)BROWS * DH;

    cvtA_kernel<<<(BROWS * (KTOT / 8)) / 256, 256, 0, stream>>>(x, h, A);
    cvtB_kernel<<<dim3(KTOT / 32, 2048 / 32), dim3(32, 8), 0, stream>>>(Wx, Wh, Bt);
    lstm_gemm_kernel<<<256, 512, 0, stream>>>(A, Bt, b, c, out_h, out_c);
}